// Round 11
// baseline (478.923 us; speedup 1.0000x reference)
//
#include <hip/hip_runtime.h>
#include <math.h>

// ConvKAN3D: 3x [conv3d(3x3x3,pad1) -> cubic KAN spline + SiLU -> BN(eval) -> maxpool 2x2x2]
// then global mean pool + fc1/relu/fc2.
// r21: DIRECT-LOAD L1/L2 (no LDS staging at all). r20's G=8 null result killed the
// DS-pressure theory: halving DS reads/FMA (conflict counter 1.049e7->5.24e6
// confirms) moved dur only 120.5->116. The staged pipeline (DMA->vmcnt->ds_read->
// lgkm) is itself the serial overhead. x (2MB) and h1 (8MB) are L3-resident and
// per-wave step working sets (~4.3KB) are L1-resident -> stage nothing: load the
// 64 r[] elements per step straight from global (zbuf pointer-select handles
// padding), identical FMA structure, scalar s_load weights. No LDS buffers, no
// barriers, no vmcnt asm in L1/L2. L3 keeps the r20 kernel verbatim (CSPLIT=4 +
// fused mean + last-block fc, measured-good).
// Measured-dead-ends (do not retry): reg-staged prefetch w/ r[64] (r18 spill),
// LDS padding/alignment (r15), TPB=128 w/ old structure (r13), 1 block/CU
// (r16-L1), separate single-block fused head (r17), G=8 acc w/ per-lane weight
// VGPRs (r8), cin-split via global atomics on conv acc (r5). launch_bounds
// (TPB,2). CSPLIT scratch indexed by (cg,sw_) jointly (r14 replay race).

#define GLOBAL_AS __attribute__((address_space(1)))
#define LDS_AS    __attribute__((address_space(3)))

static __device__ __forceinline__ void async_ld16(const float* g, float* l) {
    __builtin_amdgcn_global_load_lds((const GLOBAL_AS void*)g, (LDS_AS void*)l,
                                     16, 0, 0);
}

// Pack [C][CIN][27] conv weights -> [C*CIN][28] (16B-aligned float4 x 7, tail 0).
// Tail threads zero zbuf, pooled, and the fc completion counter (replay-safe).
__global__ __launch_bounds__(256) void repack_kernel(
    const float* __restrict__ w1, const float* __restrict__ w2,
    const float* __restrict__ w3,
    float* __restrict__ o1, float* __restrict__ o2, float* __restrict__ o3,
    float* __restrict__ zbuf, float* __restrict__ pooled,
    float* __restrict__ cntf)
{
    const int i = blockIdx.x * 256 + threadIdx.x;   // (c,ci) pair id
    const float* src;
    float* dst;
    if (i < 32)            { src = w1 + i * 27;           dst = o1 + i * 28; }
    else if (i < 2080)     { const int j = i - 32;   src = w2 + j * 27; dst = o2 + j * 28; }
    else if (i < 10272)    { const int j = i - 2080; src = w3 + j * 27; dst = o3 + j * 28; }
    else {
        if (i < 10288) zbuf[i - 10272] = 0.0f;
        else if (i < 10544) pooled[i - 10288] = 0.0f;
        else if (i < 10560) cntf[i - 10544] = 0.0f;
        return;
    }
#pragma unroll
    for (int t = 0; t < 27; t++) dst[t] = src[t];
    dst[27] = 0.0f;
}

// ---------------------------------------------------------------------------
// DIRECT-LOAD spline block (L1/L2): no LDS staging; r[] loaded straight from
// global each cin-step (L1/L3-cache served). One wave = one 2x4x8 pooled tile.
// ---------------------------------------------------------------------------
template <int TPB_, int CIN, int G, int WDT, int WHT, int WWT,
          int BD, int BH, int BW>
__global__ __launch_bounds__(TPB_, 2) void spline_direct_kernel(
    const float* __restrict__ x,    // [N, CIN, D, H, W]
    const float4* __restrict__ wpk, // [Cout*CIN][7] packed conv weights
    const float* __restrict__ cb,
    const float* __restrict__ knots,
    const float* __restrict__ sw,
    const float* __restrict__ w1,
    const float* __restrict__ w2,
    const float* __restrict__ g,
    const float* __restrict__ beta,
    const float* __restrict__ zbuf, // >=64B of zeros
    float* __restrict__ out,        // [N, Cout, D/2, H/2, W/2]
    int N, int Cout, int D, int H, int W,
    int ntiles, int nthw, int ntw)
{
    constexpr int NSW = BD * BH * BW;
    constexpr int NW  = TPB_ / 64;
    static_assert(NW == NSW, "one wave per spatial tile, no cin-split");
    static_assert(WDT * WHT * WWT == 64, "wave tile = 64 outputs");
    static_assert(G == 4, "acc layout assumes G==4");

    __shared__ float4 stbl[G * 11];            // spline prefix coeffs {A,3B,3C,D}

    const int PD = D >> 1, PH = H >> 1, PW = W >> 1;
    const int groups = Cout / G;
    const int tid  = threadIdx.x;
    const int wv   = tid >> 6;
    const int lane = tid & 63;

    const int bx      = blockIdx.x;
    const int tile_id = bx % ntiles;
    const int t1      = bx / ntiles;
    const int grp     = t1 % groups;
    const int n       = t1 / groups;
    const int c0      = grp * G;

    const int td  = tile_id / nthw;
    const int rem = tile_id % nthw;
    const int th_ = rem / ntw;
    const int tw_ = rem % ntw;

    // spline prefix-coeff table
    for (int i = tid; i < G * 11; i += TPB_) {
        const int gg  = i / 11;
        const int cnt = i % 11;
        const int c   = c0 + gg;
        float A = 0.f, B3 = 0.f, C3 = 0.f, Dd = 0.f;
        for (int j = 0; j < cnt; j++) {
            const float s = sw[c * 10 + j];
            const float k = knots[j];
            A  += s;
            B3 += 3.0f * s * k;
            C3 += 3.0f * s * k * k;
            Dd += s * k * k * k;
        }
        stbl[i] = make_float4(A, B3, C3, Dd);
    }

    // wave spatial origin (pooled coords)
    const int swd = wv / (BH * BW);
    const int r2  = wv % (BH * BW);
    const int swh = r2 / BW;
    const int sww = r2 % BW;
    const int pd0 = td  * (BD * WDT) + swd * WDT;
    const int ph0 = th_ * (BH * WHT) + swh * WHT;
    const int pw0 = tw_ * (BW * WWT) + sww * WWT;

    const int pwl = lane % WWT;
    const int phl = (lane / WWT) % WHT;
    const int pdl = lane / (WWT * WHT);

    // per-lane input coordinates: dd = ddb+dz, hh = hhb+dy, ww = wwb+j
    const int ddb = 2 * (pd0 + pdl) - 1;
    const int hhb = 2 * (ph0 + phl) - 1;
    const int wwb = 2 * (pw0 + pwl) - 1;

    int dzo[4], dyo[4];
    unsigned okd = 0, okh = 0, okw = 0;
#pragma unroll
    for (int dz = 0; dz < 4; dz++) {
        const int dd = ddb + dz;
        okd |= (unsigned)((unsigned)dd < (unsigned)D) << dz;
        dzo[dz] = dd * H * W;                  // garbage if invalid (masked)
    }
#pragma unroll
    for (int dy = 0; dy < 4; dy++) {
        const int hh = hhb + dy;
        okh |= (unsigned)((unsigned)hh < (unsigned)H) << dy;
        dyo[dy] = hh * W;
    }
#pragma unroll
    for (int j = 0; j < 4; j++)
        okw |= (unsigned)((unsigned)(wwb + j) < (unsigned)W) << j;

    const size_t chstride = (size_t)D * H * W;

    float acc[G][8];
#pragma unroll
    for (int gg = 0; gg < G; gg++)
#pragma unroll
        for (int i = 0; i < 8; i++) acc[gg][i] = 0.0f;

    __syncthreads();   // stbl visible

#pragma unroll 1
    for (int s = 0; s < CIN; s++) {
        const float* xc = x + ((size_t)n * CIN + s) * chstride;

        float r[64];
#pragma unroll
        for (int dz = 0; dz < 4; dz++)
#pragma unroll
        for (int dy = 0; dy < 4; dy++) {
            const bool rok = ((okd >> dz) & 1) & ((okh >> dy) & 1);
            const int rb = dzo[dz] + dyo[dy] + wwb;
#pragma unroll
            for (int j = 0; j < 4; j++) {
                const bool ok = rok & (bool)((okw >> j) & 1);
                const float* p = ok ? (xc + rb + j) : zbuf;
                r[(dz * 4 + dy) * 4 + j] = *p;
            }
        }

#pragma unroll
        for (int gg = 0; gg < G; gg++) {
            // uniform address -> s_load (SMEM), separate lgkm counter
            const float4* wq = wpk + ((size_t)(c0 + gg) * CIN + s) * 7;
            float4 q[7];
#pragma unroll
            for (int ch = 0; ch < 7; ch++) q[ch] = wq[ch];
#pragma unroll
            for (int ch = 0; ch < 7; ch++) {
#pragma unroll
                for (int j = 0; j < 4; j++) {
                    const int tap = ch * 4 + j;
                    if (tap < 27) {
                        const float wvj = (j == 0) ? q[ch].x : (j == 1) ? q[ch].y
                                        : (j == 2) ? q[ch].z : q[ch].w;
                        const int kd = tap / 9, kh = (tap % 9) / 3, kw = tap % 3;
#pragma unroll
                        for (int od = 0; od < 2; od++)
#pragma unroll
                        for (int oh = 0; oh < 2; oh++)
#pragma unroll
                        for (int ow = 0; ow < 2; ow++)
                            acc[gg][(od * 2 + oh) * 2 + ow] =
                                fmaf(wvj,
                                     r[((od + kd) * 4 + (oh + kh)) * 4 + (ow + kw)],
                                     acc[gg][(od * 2 + oh) * 2 + ow]);
                    }
                }
            }
        }
    }

    // epilogue: bias + spline (prefix-Horner) + SiLU + BN + maxpool
    {
        const int pdg = pd0 + pdl, phg = ph0 + phl, pwg = pw0 + pwl;
#pragma unroll
        for (int gg = 0; gg < G; gg++) {
            const int c = c0 + gg;
            const float bias = cb[c];
            const float W1 = w1[c], W2 = w2[c];
            const float scale = g[c] * rsqrtf(1.0f + 1e-5f);
            const float bb = beta[c];
            float m = -INFINITY;
#pragma unroll
            for (int i = 0; i < 8; i++) {
                const float y = acc[gg][i] + bias;
                int idx = (int)floorf((y + 1.0f) * 4.5f) + 1;
                idx = min(max(idx, 0), 10);
                const float4 cf = stbl[gg * 11 + idx];
                const float sp = ((cf.x * y - cf.y) * y + cf.z) * y - cf.w;
                const float silu = y / (1.0f + __expf(-y));
                const float o = fmaf(W1 * sp + W2 * silu, scale, bb);
                m = fmaxf(m, o);
            }
            out[((size_t)(n * Cout + c) * PD + pdg) * PH * PW + phg * PW + pwg] = m;
        }
    }
}

// ---------------------------------------------------------------------------
// LDS-staged spline block (L3 only): r20 form verbatim — CSPLIT cin-split,
// dbuf DMA + vmcnt(6), fused global-mean (atomicAdd) + last-block fc head.
// ---------------------------------------------------------------------------
template <int TPB_, int CIN, int CSPLIT, int G,
          int WDT, int WHT, int WWT, int BD, int BH, int BW, bool FMEAN>
__global__ __launch_bounds__(TPB_, 2) void spline_block_kernel(
    const float* __restrict__ x,
    const float4* __restrict__ wpk,
    const float* __restrict__ cb,
    const float* __restrict__ knots,
    const float* __restrict__ sw,
    const float* __restrict__ w1,
    const float* __restrict__ w2,
    const float* __restrict__ g,
    const float* __restrict__ beta,
    const float* __restrict__ zbuf,
    float* __restrict__ out,
    const float* __restrict__ fw1, const float* __restrict__ fb1,
    const float* __restrict__ fw2, const float* __restrict__ fb2,
    float* __restrict__ dout, int* __restrict__ cnt,
    int N, int Cout, int D, int H, int W,
    int ntiles, int nthw, int ntw)
{
    constexpr int NSW    = BD * BH * BW;
    constexpr int NW     = TPB_ / 64;
    constexpr int CPG    = CIN / CSPLIT;
    constexpr int ID     = 2 * WDT + 2;
    constexpr int IH     = 2 * WHT + 2;
    constexpr int CHK    = (WWT + 4) / 2;
    constexpr int PITCH  = CHK * 4;
    constexpr int ROWS   = ID * IH;
    constexpr int CHUNKS = ROWS * CHK;
    constexpr int PHYS   = CHUNKS * 4;
    constexpr int NCH    = (CHUNKS + 63) / 64;
    constexpr int BUFS   = (CPG > 1) ? 2 : 1;
    static_assert(NW == NSW * CSPLIT, "waves = spatial-tiles x cin-split");
    static_assert(WDT * WHT * WWT == 64, "one wave per spatial tile");
    static_assert(CIN % CSPLIT == 0, "cin divisible");
    static_assert(G == 4, "acc layout assumes G==4");
    static_assert(NCH == 6, "s_waitcnt vmcnt(6) literal assumes 6 issues/cin");
    static_assert(CSPLIT == 1 ||
                  (CSPLIT - 1) * NSW * 64 * G * 8 <= NW * BUFS * PHYS,
                  "reduction scratch fits in tile");
    static_assert(!FMEAN || TPB_ == 256, "fused fc assumes 256 threads");

    __shared__ __align__(16) float tile[NW][BUFS][PHYS];
    __shared__ float4 stbl[G * 11];
    __shared__ int lastblk;

    const int PD = D >> 1, PH = H >> 1, PW = W >> 1;
    const int groups = Cout / G;
    const int tid  = threadIdx.x;
    const int wv   = tid >> 6;
    const int lane = tid & 63;
    const int sw_  = wv % NSW;
    const int cg   = wv / NSW;

    const int bx      = blockIdx.x;
    const int tile_id = bx % ntiles;
    const int t1      = bx / ntiles;
    const int grp     = t1 % groups;
    const int n       = t1 / groups;
    const int c0      = grp * G;
    const int cinbase = cg * CPG;
    const int cinbase_u = __builtin_amdgcn_readfirstlane(cinbase);

    const int td  = tile_id / nthw;
    const int rem = tile_id % nthw;
    const int th_ = rem / ntw;
    const int tw_ = rem % ntw;

    for (int i = tid; i < G * 11; i += TPB_) {
        const int gg  = i / 11;
        const int cnt2 = i % 11;
        const int c   = c0 + gg;
        float A = 0.f, B3 = 0.f, C3 = 0.f, Dd = 0.f;
        for (int j = 0; j < cnt2; j++) {
            const float s = sw[c * 10 + j];
            const float k = knots[j];
            A  += s;
            B3 += 3.0f * s * k;
            C3 += 3.0f * s * k * k;
            Dd += s * k * k * k;
        }
        stbl[i] = make_float4(A, B3, C3, Dd);
    }

    const int swd = sw_ / (BH * BW);
    const int r2  = sw_ % (BH * BW);
    const int swh = r2 / BW;
    const int sww = r2 % BW;
    const int pd0 = td  * (BD * WDT) + swd * WDT;
    const int ph0 = th_ * (BH * WHT) + swh * WHT;
    const int pw0 = tw_ * (BW * WWT) + sww * WWT;

    const int pwl = lane % WWT;
    const int phl = (lane / WWT) % WHT;
    const int pdl = lane / (WWT * WHT);

    const int d0 = 2 * pd0 - 1, h0 = 2 * ph0 - 1;
    const int w0 = 2 * pw0 - 1;
    const int wb = w0 & ~3;
    const int woff = w0 - wb;

    int off[NCH];
    unsigned vm = 0;
#pragma unroll
    for (int k = 0; k < NCH; k++) {
        const int chunk = lane + 64 * k;
        const int row = chunk / CHK, cs = chunk - row * CHK;
        const int dz = row / IH, hy = row - dz * IH;
        const int dd = d0 + dz, hh = h0 + hy;
        const int wsd = wb + cs * 4;
        const bool ok = (chunk < CHUNKS) &
                        ((unsigned)dd < (unsigned)D) &
                        ((unsigned)hh < (unsigned)H) &
                        ((unsigned)wsd < (unsigned)W);
        off[k] = ok ? (dd * H + hh) * W + wsd : 0;
        vm |= (unsigned)ok << k;
    }

    const size_t chstride = (size_t)D * H * W;
    const float* xn = x + (size_t)n * CIN * chstride;

    float acc[G][8];
#pragma unroll
    for (int gg = 0; gg < G; gg++)
#pragma unroll
        for (int i = 0; i < 8; i++) acc[gg][i] = 0.0f;

    __syncthreads();

    auto stage = [&](int ci, int buf) {
        const float* xc = xn + (size_t)ci * chstride;
        float* dst = &tile[wv][buf][0];
#pragma unroll
        for (int k = 0; k < NCH; k++) {
            const int chunk = lane + 64 * k;
            if ((k + 1) * 64 <= CHUNKS || chunk < CHUNKS) {
                const float* src = ((vm >> k) & 1) ? (xc + off[k]) : zbuf;
                async_ld16(src, dst + chunk * 4);
            }
        }
    };

    stage(cinbase, 0);

#pragma unroll 1
    for (int s = 0; s < CPG; s++) {
        const int cur = s & (BUFS - 1);
        if (s + 1 < CPG) {
            stage(cinbase + s + 1, cur ^ 1);
            asm volatile("s_waitcnt vmcnt(6)" ::: "memory");
        } else {
            asm volatile("s_waitcnt vmcnt(0)" ::: "memory");
        }

        const int ci_u = cinbase_u + s;
        const float* tb = &tile[wv][cur][0];
        float r[64];
#pragma unroll
        for (int dz = 0; dz < 4; dz++)
#pragma unroll
        for (int dy = 0; dy < 4; dy++) {
            const int rb = ((2 * pdl + dz) * IH + (2 * phl + dy)) * PITCH +
                           woff + 2 * pwl;
            r[(dz * 4 + dy) * 4 + 0] = tb[rb + 0];
            r[(dz * 4 + dy) * 4 + 1] = tb[rb + 1];
            r[(dz * 4 + dy) * 4 + 2] = tb[rb + 2];
            r[(dz * 4 + dy) * 4 + 3] = tb[rb + 3];
        }

#pragma unroll
        for (int gg = 0; gg < G; gg++) {
            const float4* wq = wpk + ((size_t)(c0 + gg) * CIN + ci_u) * 7;
            float4 q[7];
#pragma unroll
            for (int ch = 0; ch < 7; ch++) q[ch] = wq[ch];
#pragma unroll
            for (int ch = 0; ch < 7; ch++) {
#pragma unroll
                for (int j = 0; j < 4; j++) {
                    const int tap = ch * 4 + j;
                    if (tap < 27) {
                        const float wvj = (j == 0) ? q[ch].x : (j == 1) ? q[ch].y
                                        : (j == 2) ? q[ch].z : q[ch].w;
                        const int kd = tap / 9, kh = (tap % 9) / 3, kw = tap % 3;
#pragma unroll
                        for (int od = 0; od < 2; od++)
#pragma unroll
                        for (int oh = 0; oh < 2; oh++)
#pragma unroll
                        for (int ow = 0; ow < 2; ow++)
                            acc[gg][(od * 2 + oh) * 2 + ow] =
                                fmaf(wvj,
                                     r[((od + kd) * 4 + (oh + kh)) * 4 + (ow + kw)],
                                     acc[gg][(od * 2 + oh) * 2 + ow]);
                    }
                }
            }
        }
    }

    float* af = &acc[0][0];
    if (CSPLIT > 1) {
        __syncthreads();
        float* scratch = &tile[0][0][0];
        if (cg > 0) {
#pragma unroll
            for (int idx = 0; idx < G * 8; idx++)
                scratch[((idx * (CSPLIT - 1) + (cg - 1)) * NSW + sw_) * 64 + lane]
                    = af[idx];
        }
        __syncthreads();
        if (cg == 0) {
#pragma unroll
            for (int idx = 0; idx < G * 8; idx++) {
                float s2 = af[idx];
                for (int j = 0; j < CSPLIT - 1; j++)
                    s2 += scratch[((idx * (CSPLIT - 1) + j) * NSW + sw_) * 64 + lane];
                af[idx] = s2;
            }
        }
    }

    if (cg == 0) {
        const int pdg = pd0 + pdl, phg = ph0 + phl, pwg = pw0 + pwl;
        const float inv_vol = 1.0f / (float)(PD * PH * PW);
#pragma unroll
        for (int gg = 0; gg < G; gg++) {
            const int c = c0 + gg;
            const float bias = cb[c];
            const float W1 = w1[c], W2 = w2[c];
            const float scale = g[c] * rsqrtf(1.0f + 1e-5f);
            const float bb = beta[c];
            float m = -INFINITY;
#pragma unroll
            for (int i = 0; i < 8; i++) {
                const float y = acc[gg][i] + bias;
                int idx = (int)floorf((y + 1.0f) * 4.5f) + 1;
                idx = min(max(idx, 0), 10);
                const float4 cf = stbl[gg * 11 + idx];
                const float sp = ((cf.x * y - cf.y) * y + cf.z) * y - cf.w;
                const float silu = y / (1.0f + __expf(-y));
                const float o = fmaf(W1 * sp + W2 * silu, scale, bb);
                m = fmaxf(m, o);
            }
            if constexpr (FMEAN) {
                float ssum = m;
#pragma unroll
                for (int o2 = 32; o2 > 0; o2 >>= 1)
                    ssum += __shfl_down(ssum, o2, 64);
                if (lane == 0)
                    atomicAdd(&out[(size_t)n * Cout + c], ssum * inv_vol);
            } else {
                out[((size_t)(n * Cout + c) * PD + pdg) * PH * PW +
                    phg * PW + pwg] = m;
            }
        }
    }

    if constexpr (FMEAN) {
        __syncthreads();
        if (tid == 0) {
            __threadfence();
            lastblk = (atomicAdd(cnt, 1) == (int)gridDim.x - 1);
        }
        __syncthreads();
        if (lastblk) {
            __threadfence();
            float* fl = &tile[0][0][0];
            fl[tid] = atomicAdd(&out[tid], 0.0f);
            __syncthreads();
#pragma unroll
            for (int nn = 0; nn < 2; nn++) {
                float s = fb1[tid];
                for (int k = 0; k < 128; k++)
                    s = fmaf(fl[nn * 128 + k], fw1[tid * 128 + k], s);
                fl[256 + nn * 256 + tid] = fmaxf(s, 0.0f);
            }
            __syncthreads();
            const int wid = tid >> 6, l2 = tid & 63;
            const int nn = wid >> 1, oo = wid & 1;
            float s = 0.0f;
            for (int k = l2; k < 256; k += 64)
                s += fl[256 + nn * 256 + k] * fw2[oo * 256 + k];
#pragma unroll
            for (int o2 = 32; o2 > 0; o2 >>= 1) s += __shfl_down(s, o2, 64);
            if (l2 == 0) dout[nn * 2 + oo] = s + fb2[oo];
        }
    }
}

extern "C" void kernel_launch(void* const* d_in, const int* in_sizes, int n_in,
                              void* d_out, int out_size, void* d_ws, size_t ws_size,
                              hipStream_t stream) {
    const float* x      = (const float*)d_in[0];
    const float* c1_w   = (const float*)d_in[1];
    const float* c1_b   = (const float*)d_in[2];
    const float* c1_kn  = (const float*)d_in[3];
    const float* c1_sw  = (const float*)d_in[4];
    const float* c1_w1  = (const float*)d_in[5];
    const float* c1_w2  = (const float*)d_in[6];
    const float* bn1_g  = (const float*)d_in[7];
    const float* bn1_b  = (const float*)d_in[8];
    const float* c2_w   = (const float*)d_in[9];
    const float* c2_b   = (const float*)d_in[10];
    const float* c2_kn  = (const float*)d_in[11];
    const float* c2_sw  = (const float*)d_in[12];
    const float* c2_w1  = (const float*)d_in[13];
    const float* c2_w2  = (const float*)d_in[14];
    const float* bn2_g  = (const float*)d_in[15];
    const float* bn2_b  = (const float*)d_in[16];
    const float* c3_w   = (const float*)d_in[17];
    const float* c3_b   = (const float*)d_in[18];
    const float* c3_kn  = (const float*)d_in[19];
    const float* c3_sw  = (const float*)d_in[20];
    const float* c3_w1  = (const float*)d_in[21];
    const float* c3_w2  = (const float*)d_in[22];
    const float* bn3_g  = (const float*)d_in[23];
    const float* bn3_b  = (const float*)d_in[24];
    const float* fc1_w  = (const float*)d_in[25];
    const float* fc1_b  = (const float*)d_in[26];
    const float* fc2_w  = (const float*)d_in[27];
    const float* fc2_b  = (const float*)d_in[28];

    float* ws = (float*)d_ws;
    float* h1     = ws;                  // 2*32*32^3 = 2,097,152 fl
    float* h2     = h1 + 2097152;        // 2*64*16^3 =   524,288 fl
    float* pooled = h2 + 524288;         // 256 fl (atomic accumulator)
    float* zbuf   = pooled + 256;        // 64 B zeros (16B aligned)
    float* cntf   = zbuf + 16;           // 16 fl (fc completion counter at [0])
    float* wp1    = cntf + 16;           // 32*1*28   =       896 fl (16B aligned)
    float* wp2    = wp1 + 896;           // 64*32*28  =    57,344 fl
    float* wp3    = wp2 + 57344;         // 128*64*28 =   229,376 fl

    // pack conv weights (pitch-28 float4x7) + zero zbuf/pooled/cnt (replay-safe)
    repack_kernel<<<dim3(42), dim3(256), 0, stream>>>(
        c1_w, c2_w, c3_w, wp1, wp2, wp3, zbuf, pooled, cntf);

    // L1 (direct): (2,1,64^3)->(2,32,32^3). 4 spatial waves (2x2x1), block tile
    // 4x8x8; x (2MB) is L2/L3-resident -> no staging. grid = 2*8*128 = 2048.
    spline_direct_kernel<256, 1, 4, 2, 4, 8, 2, 2, 1>
        <<<dim3(2048), dim3(256), 0, stream>>>(
        x, (const float4*)wp1, c1_b, c1_kn, c1_sw, c1_w1, c1_w2, bn1_g, bn1_b,
        zbuf, h1, 2, 32, 64, 64, 64, 128, 16, 4);
    // L2 (direct): (2,32,32^3)->(2,64,16^3). 4 spatial waves (2x2x1), block tile
    // 4x8x8; h1 (8MB) is L3-resident, per-step working set L1-resident.
    // grid = 2*16*16 = 512.
    spline_direct_kernel<256, 32, 4, 2, 4, 8, 2, 2, 1>
        <<<dim3(512), dim3(256), 0, stream>>>(
        h1, (const float4*)wp2, c2_b, c2_kn, c2_sw, c2_w1, c2_w2, bn2_g, bn2_b,
        zbuf, h2, 2, 64, 32, 32, 32, 16, 4, 2);
    // L3 (staged, r20 verbatim): (2,64,16^3)->pooled (FMEAN) + last-block fc.
    // CSPLIT=4, grid 512.
    spline_block_kernel<256, 64, 4, 4, 2, 4, 8, 1, 1, 1, true>
        <<<dim3(512), dim3(256), 0, stream>>>(
        h2, (const float4*)wp3, c3_b, c3_kn, c3_sw, c3_w1, c3_w2, bn3_g, bn3_b,
        zbuf, pooled, fc1_w, fc1_b, fc2_w, fc2_b, (float*)d_out, (int*)cntf,
        2, 128, 16, 16, 16, 8, 2, 1);
}

// Round 13
// 318.572 us; speedup vs baseline: 1.5033x; 1.5033x over previous
//
#include <hip/hip_runtime.h>
#include <math.h>

// ConvKAN3D: 3x [conv3d(3x3x3,pad1) -> cubic KAN spline + SiLU -> BN(eval) -> maxpool 2x2x2]
// then global mean pool + fc1/relu/fc2.
// r23: r22 with the scratch-capacity bug fixed. r22's L2 shape (CSPLIT=4 x NSW=1,
// G=8 -> CPG=8, grid 1024) needed 12288 dw of reduction scratch but the tile alias
// holds 11520 dw (static_assert caught it). Fix: MULTI-PASS reduction — split the
// G*8 accumulator indices into PASSES chunks (constexpr: 2 for L2's config, 1 for
// L3 -> L3 codegen unchanged), barrier per pass. Scratch/pass = 6144 dw, fits.
// Rationale (unchanged from r22): at identical MAC counts, L3's CSPLIT=4/NSW=1
// shape ran ~71% of its FMA floor while every NSW=2 L2 shape ran ~40% across three
// killed theories (DS pressure r20, LDS-occupancy r17/r18, weight path r16).
// Measured-dead-ends (do not retry): direct per-lane global r[] loads (r21: 264us,
// TA/L1 saturation), reg-staged prefetch w/ r[64] (r18 spill), LDS pad/align (r15),
// TPB=128 (r13), 1 block/CU (r16), separate fused 1-block head (r17), G=8 w/
// per-lane weight VGPRs (r8), conv-acc via global atomics (r5). launch_bounds
// stays (TPB,2). CSPLIT scratch indexed by (cg,sw_) (r14 race).

#define GLOBAL_AS __attribute__((address_space(1)))
#define LDS_AS    __attribute__((address_space(3)))

static __device__ __forceinline__ void async_ld16(const float* g, float* l) {
    __builtin_amdgcn_global_load_lds((const GLOBAL_AS void*)g, (LDS_AS void*)l,
                                     16, 0, 0);
}

// Pack [C][CIN][27] conv weights -> [C*CIN][28] (16B-aligned float4 x 7, tail 0).
// Tail threads zero zbuf, pooled, and the fc completion counter (replay-safe).
__global__ __launch_bounds__(256) void repack_kernel(
    const float* __restrict__ w1, const float* __restrict__ w2,
    const float* __restrict__ w3,
    float* __restrict__ o1, float* __restrict__ o2, float* __restrict__ o3,
    float* __restrict__ zbuf, float* __restrict__ pooled,
    float* __restrict__ cntf)
{
    const int i = blockIdx.x * 256 + threadIdx.x;   // (c,ci) pair id
    const float* src;
    float* dst;
    if (i < 32)            { src = w1 + i * 27;           dst = o1 + i * 28; }
    else if (i < 2080)     { const int j = i - 32;   src = w2 + j * 27; dst = o2 + j * 28; }
    else if (i < 10272)    { const int j = i - 2080; src = w3 + j * 27; dst = o3 + j * 28; }
    else {
        if (i < 10288) zbuf[i - 10272] = 0.0f;
        else if (i < 10544) pooled[i - 10288] = 0.0f;
        else if (i < 10560) cntf[i - 10544] = 0.0f;
        return;
    }
#pragma unroll
    for (int t = 0; t < 27; t++) dst[t] = src[t];
    dst[27] = 0.0f;
}

template <int TPB_, int CIN, int CSPLIT, int G,
          int WDT, int WHT, int WWT, int BD, int BH, int BW, bool FMEAN>
__global__ __launch_bounds__(TPB_, 2) void spline_block_kernel(
    const float* __restrict__ x,    // [N, CIN, D, H, W]
    const float4* __restrict__ wpk, // [Cout*CIN][7] packed conv weights
    const float* __restrict__ cb,
    const float* __restrict__ knots,
    const float* __restrict__ sw,
    const float* __restrict__ w1,
    const float* __restrict__ w2,
    const float* __restrict__ g,
    const float* __restrict__ beta,
    const float* __restrict__ zbuf, // >=64B of zeros (16B aligned)
    float* __restrict__ out,        // FMEAN? pooled[N*Cout] : [N,Cout,D/2,H/2,W/2]
    const float* __restrict__ fw1, const float* __restrict__ fb1,
    const float* __restrict__ fw2, const float* __restrict__ fb2,
    float* __restrict__ dout, int* __restrict__ cnt,
    int N, int Cout, int D, int H, int W,
    int ntiles, int nthw, int ntw)
{
    constexpr int NSW    = BD * BH * BW;       // spatial wave-tiles per block
    constexpr int NW     = TPB_ / 64;          // waves per block
    constexpr int CPG    = CIN / CSPLIT;       // cins per cin-group
    constexpr int ID     = 2 * WDT + 2;        // input planes (d) per wave tile
    constexpr int IH     = 2 * WHT + 2;        // input rows (h) per wave tile
    constexpr int CHK    = (WWT + 4) / 2;      // 16B chunks per input row
    constexpr int PITCH  = CHK * 4;            // dwords per row
    constexpr int ROWS   = ID * IH;
    constexpr int CHUNKS = ROWS * CHK;
    constexpr int PHYS   = CHUNKS * 4;         // dwords per wave buffer
    constexpr int NCH    = (CHUNKS + 63) / 64; // DMA issues per cin per lane
    constexpr int BUFS   = (CPG > 1) ? 2 : 1;
    // multi-pass reduction sizing: scratch aliases the tile; if one pass doesn't
    // fit, split the G*8 accumulator indices across 2 passes (r22 compile fail).
    constexpr int RED    = G * 8;              // accumulator dwords per thread
    constexpr int CAP    = NW * BUFS * PHYS;   // tile capacity (dwords)
    constexpr int PASSES = (CSPLIT == 1) ? 1
                         : (((CSPLIT - 1) * NSW * 64 * RED <= CAP) ? 1 : 2);
    constexpr int RPP    = RED / PASSES;       // indices per pass
    static_assert(NW == NSW * CSPLIT, "waves = spatial-tiles x cin-split");
    static_assert(WDT * WHT * WWT == 64, "one wave per spatial tile");
    static_assert(CIN % CSPLIT == 0, "cin divisible");
    static_assert(G == 4 || G == 8, "acc layout assumes G in {4,8}");
    static_assert(RED % PASSES == 0, "even pass split");
    static_assert(NCH <= 32, "mask fits u32");
    static_assert(NCH == 6, "s_waitcnt vmcnt(6) literal assumes 6 issues/cin");
    static_assert(CSPLIT == 1 ||
                  (CSPLIT - 1) * NSW * 64 * RPP <= CAP,
                  "reduction scratch fits in tile (per pass)");
    static_assert(!FMEAN || TPB_ == 256, "fused fc assumes 256 threads");

    __shared__ __align__(16) float tile[NW][BUFS][PHYS];
    __shared__ float4 stbl[G * 11];            // spline prefix coeffs {A,3B,3C,D}
    __shared__ int lastblk;

    const int PD = D >> 1, PH = H >> 1, PW = W >> 1;
    const int groups = Cout / G;
    const int tid  = threadIdx.x;
    const int wv   = tid >> 6;                 // wave id
    const int lane = tid & 63;
    const int sw_  = wv % NSW;                 // spatial wave-tile id
    const int cg   = wv / NSW;                 // cin-group id

    const int bx      = blockIdx.x;
    const int tile_id = bx % ntiles;
    const int t1      = bx / ntiles;
    const int grp     = t1 % groups;
    const int n       = t1 / groups;
    const int c0      = grp * G;
    const int cinbase = cg * CPG;
    // wave-uniform cin base -> uniform weight addresses -> SMEM s_load (lgkmcnt,
    // separate counter from the staging DMAs' vmcnt, zero VGPR cost)
    const int cinbase_u = __builtin_amdgcn_readfirstlane(cinbase);

    const int td  = tile_id / nthw;
    const int rem = tile_id % nthw;
    const int th_ = rem / ntw;
    const int tw_ = rem % ntw;

    // spline prefix-coeff table (covered by the single initial barrier)
    for (int i = tid; i < G * 11; i += TPB_) {
        const int gg  = i / 11;
        const int cnt2 = i % 11;
        const int c   = c0 + gg;
        float A = 0.f, B3 = 0.f, C3 = 0.f, Dd = 0.f;
        for (int j = 0; j < cnt2; j++) {
            const float s = sw[c * 10 + j];
            const float k = knots[j];
            A  += s;
            B3 += 3.0f * s * k;
            C3 += 3.0f * s * k * k;
            Dd += s * k * k * k;
        }
        stbl[i] = make_float4(A, B3, C3, Dd);
    }

    // wave spatial origin (pooled coords)
    const int swd = sw_ / (BH * BW);
    const int r2  = sw_ % (BH * BW);
    const int swh = r2 / BW;
    const int sww = r2 % BW;
    const int pd0 = td  * (BD * WDT) + swd * WDT;
    const int ph0 = th_ * (BH * WHT) + swh * WHT;
    const int pw0 = tw_ * (BW * WWT) + sww * WWT;

    const int pwl = lane % WWT;
    const int phl = (lane / WWT) % WHT;
    const int pdl = lane / (WWT * WHT);

    const int d0 = 2 * pd0 - 1, h0 = 2 * ph0 - 1;
    const int w0 = 2 * pw0 - 1;
    const int wb = w0 & ~3;                    // 4-dword aligned chunk origin
    const int woff = w0 - wb;

    // per-chunk global offsets + validity (per wave tile, same for all cins)
    int off[NCH];
    unsigned vm = 0;
#pragma unroll
    for (int k = 0; k < NCH; k++) {
        const int chunk = lane + 64 * k;
        const int row = chunk / CHK, cs = chunk - row * CHK;
        const int dz = row / IH, hy = row - dz * IH;
        const int dd = d0 + dz, hh = h0 + hy;
        const int wsd = wb + cs * 4;
        const bool ok = (chunk < CHUNKS) &
                        ((unsigned)dd < (unsigned)D) &
                        ((unsigned)hh < (unsigned)H) &
                        ((unsigned)wsd < (unsigned)W);
        off[k] = ok ? (dd * H + hh) * W + wsd : 0;
        vm |= (unsigned)ok << k;
    }

    const size_t chstride = (size_t)D * H * W;
    const float* xn = x + (size_t)n * CIN * chstride;

    float acc[G][8];
#pragma unroll
    for (int gg = 0; gg < G; gg++)
#pragma unroll
        for (int i = 0; i < 8; i++) acc[gg][i] = 0.0f;

    __syncthreads();   // stbl visible; vmcnt drained (clean slate)

    auto stage = [&](int ci, int buf) {
        const float* xc = xn + (size_t)ci * chstride;
        float* dst = &tile[wv][buf][0];
#pragma unroll
        for (int k = 0; k < NCH; k++) {
            const int chunk = lane + 64 * k;
            if ((k + 1) * 64 <= CHUNKS || chunk < CHUNKS) {
                const float* src = ((vm >> k) & 1) ? (xc + off[k]) : zbuf;
                async_ld16(src, dst + chunk * 4);
            }
        }
    };

    // prologue: each wave stages its first cin into its buf 0
    stage(cinbase, 0);

#pragma unroll 1
    for (int s = 0; s < CPG; s++) {
        const int cur = s & (BUFS - 1);
        if (s + 1 < CPG) {
            stage(cinbase + s + 1, cur ^ 1);   // 6 DMA issues, stay in flight
            asm volatile("s_waitcnt vmcnt(6)" ::: "memory");  // cin s landed
        } else {
            asm volatile("s_waitcnt vmcnt(0)" ::: "memory");
        }

        const int ci_u = cinbase_u + s;        // wave-uniform weight row
        const float* tb = &tile[wv][cur][0];
        float r[64];
#pragma unroll
        for (int dz = 0; dz < 4; dz++)
#pragma unroll
        for (int dy = 0; dy < 4; dy++) {
            const int rb = ((2 * pdl + dz) * IH + (2 * phl + dy)) * PITCH +
                           woff + 2 * pwl;
            r[(dz * 4 + dy) * 4 + 0] = tb[rb + 0];
            r[(dz * 4 + dy) * 4 + 1] = tb[rb + 1];
            r[(dz * 4 + dy) * 4 + 2] = tb[rb + 2];
            r[(dz * 4 + dy) * 4 + 3] = tb[rb + 3];
        }

#pragma unroll
        for (int gg = 0; gg < G; gg++) {
            // uniform address -> s_load (SMEM), separate lgkm counter
            const float4* wq = wpk + ((size_t)(c0 + gg) * CIN + ci_u) * 7;
            float4 q[7];
#pragma unroll
            for (int ch = 0; ch < 7; ch++) q[ch] = wq[ch];
#pragma unroll
            for (int ch = 0; ch < 7; ch++) {
#pragma unroll
                for (int j = 0; j < 4; j++) {
                    const int tap = ch * 4 + j;
                    if (tap < 27) {
                        const float wvj = (j == 0) ? q[ch].x : (j == 1) ? q[ch].y
                                        : (j == 2) ? q[ch].z : q[ch].w;
                        const int kd = tap / 9, kh = (tap % 9) / 3, kw = tap % 3;
#pragma unroll
                        for (int od = 0; od < 2; od++)
#pragma unroll
                        for (int oh = 0; oh < 2; oh++)
#pragma unroll
                        for (int ow = 0; ow < 2; ow++)
                            acc[gg][(od * 2 + oh) * 2 + ow] =
                                fmaf(wvj,
                                     r[((od + kd) * 4 + (oh + kh)) * 4 + (ow + kw)],
                                     acc[gg][(od * 2 + oh) * 2 + ow]);
                    }
                }
            }
        }
    }

    // combine partial accumulators across cin-groups (scratch aliases tile),
    // in PASSES chunks of RPP indices (capacity-limited; r22 compile fail).
    // scratch MUST be indexed by (cg, sw_) jointly (r14 replay race).
    float* af = &acc[0][0];
    if (CSPLIT > 1) {
#pragma unroll
        for (int p = 0; p < PASSES; p++) {
            __syncthreads();   // p=0: waves done with tiles; p>0: readers done
            float* scratch = &tile[0][0][0];
            if (cg > 0) {
#pragma unroll
                for (int ii = 0; ii < RPP; ii++)
                    scratch[((ii * (CSPLIT - 1) + (cg - 1)) * NSW + sw_) * 64 + lane]
                        = af[p * RPP + ii];
            }
            __syncthreads();
            if (cg == 0) {
#pragma unroll
                for (int ii = 0; ii < RPP; ii++) {
                    float s2 = af[p * RPP + ii];
                    for (int j = 0; j < CSPLIT - 1; j++)
                        s2 += scratch[((ii * (CSPLIT - 1) + j) * NSW + sw_) * 64 + lane];
                    af[p * RPP + ii] = s2;
                }
            }
        }
    }

    // epilogue (cin-group 0): bias + spline (prefix-Horner) + SiLU + BN + maxpool
    if (cg == 0) {
        const int pdg = pd0 + pdl, phg = ph0 + phl, pwg = pw0 + pwl;
        const float inv_vol = 1.0f / (float)(PD * PH * PW);
#pragma unroll
        for (int gg = 0; gg < G; gg++) {
            const int c = c0 + gg;
            const float bias = cb[c];
            const float W1 = w1[c], W2 = w2[c];
            const float scale = g[c] * rsqrtf(1.0f + 1e-5f);
            const float bb = beta[c];
            float m = -INFINITY;
#pragma unroll
            for (int i = 0; i < 8; i++) {
                const float y = acc[gg][i] + bias;
                int idx = (int)floorf((y + 1.0f) * 4.5f) + 1;
                idx = min(max(idx, 0), 10);
                const float4 cf = stbl[gg * 11 + idx];
                const float sp = ((cf.x * y - cf.y) * y + cf.z) * y - cf.w;
                const float silu = y / (1.0f + __expf(-y));
                const float o = fmaf(W1 * sp + W2 * silu, scale, bb);
                m = fmaxf(m, o);
            }
            if constexpr (FMEAN) {
                float ssum = m;
#pragma unroll
                for (int o2 = 32; o2 > 0; o2 >>= 1)
                    ssum += __shfl_down(ssum, o2, 64);
                if (lane == 0)
                    atomicAdd(&out[(size_t)n * Cout + c], ssum * inv_vol);
            } else {
                out[((size_t)(n * Cout + c) * PD + pdg) * PH * PW +
                    phg * PW + pwg] = m;
            }
        }
    }

    // fused fc head: LAST block (device-scope counter) computes fc1/fc2.
    if constexpr (FMEAN) {
        __syncthreads();   // per-wave vmcnt(0) drain -> all atomics retired
        if (tid == 0) {
            __threadfence();                         // publish this block's adds
            lastblk = (atomicAdd(cnt, 1) == (int)gridDim.x - 1);
        }
        __syncthreads();
        if (lastblk) {
            __threadfence();                         // order before coherent reads
            float* fl = &tile[0][0][0];              // plds[256] | hb[2][256]
            fl[tid] = atomicAdd(&out[tid], 0.0f);    // coherent read of pooled
            __syncthreads();
#pragma unroll
            for (int nn = 0; nn < 2; nn++) {
                float s = fb1[tid];
                for (int k = 0; k < 128; k++)
                    s = fmaf(fl[nn * 128 + k], fw1[tid * 128 + k], s);
                fl[256 + nn * 256 + tid] = fmaxf(s, 0.0f);
            }
            __syncthreads();
            const int wid = tid >> 6, l2 = tid & 63;
            const int nn = wid >> 1, oo = wid & 1;
            float s = 0.0f;
            for (int k = l2; k < 256; k += 64)
                s += fl[256 + nn * 256 + k] * fw2[oo * 256 + k];
#pragma unroll
            for (int o2 = 32; o2 > 0; o2 >>= 1) s += __shfl_down(s, o2, 64);
            if (l2 == 0) dout[nn * 2 + oo] = s + fb2[oo];
        }
    }
}

extern "C" void kernel_launch(void* const* d_in, const int* in_sizes, int n_in,
                              void* d_out, int out_size, void* d_ws, size_t ws_size,
                              hipStream_t stream) {
    const float* x      = (const float*)d_in[0];
    const float* c1_w   = (const float*)d_in[1];
    const float* c1_b   = (const float*)d_in[2];
    const float* c1_kn  = (const float*)d_in[3];
    const float* c1_sw  = (const float*)d_in[4];
    const float* c1_w1  = (const float*)d_in[5];
    const float* c1_w2  = (const float*)d_in[6];
    const float* bn1_g  = (const float*)d_in[7];
    const float* bn1_b  = (const float*)d_in[8];
    const float* c2_w   = (const float*)d_in[9];
    const float* c2_b   = (const float*)d_in[10];
    const float* c2_kn  = (const float*)d_in[11];
    const float* c2_sw  = (const float*)d_in[12];
    const float* c2_w1  = (const float*)d_in[13];
    const float* c2_w2  = (const float*)d_in[14];
    const float* bn2_g  = (const float*)d_in[15];
    const float* bn2_b  = (const float*)d_in[16];
    const float* c3_w   = (const float*)d_in[17];
    const float* c3_b   = (const float*)d_in[18];
    const float* c3_kn  = (const float*)d_in[19];
    const float* c3_sw  = (const float*)d_in[20];
    const float* c3_w1  = (const float*)d_in[21];
    const float* c3_w2  = (const float*)d_in[22];
    const float* bn3_g  = (const float*)d_in[23];
    const float* bn3_b  = (const float*)d_in[24];
    const float* fc1_w  = (const float*)d_in[25];
    const float* fc1_b  = (const float*)d_in[26];
    const float* fc2_w  = (const float*)d_in[27];
    const float* fc2_b  = (const float*)d_in[28];

    float* ws = (float*)d_ws;
    float* h1     = ws;                  // 2*32*32^3 = 2,097,152 fl
    float* h2     = h1 + 2097152;        // 2*64*16^3 =   524,288 fl
    float* pooled = h2 + 524288;         // 256 fl (atomic accumulator)
    float* zbuf   = pooled + 256;        // 64 B zeros (16B aligned)
    float* cntf   = zbuf + 16;           // 16 fl (fc completion counter at [0])
    float* wp1    = cntf + 16;           // 32*1*28   =       896 fl (16B aligned)
    float* wp2    = wp1 + 896;           // 64*32*28  =    57,344 fl
    float* wp3    = wp2 + 57344;         // 128*64*28 =   229,376 fl

    // pack conv weights (pitch-28 float4x7) + zero zbuf/pooled/cnt (replay-safe)
    repack_kernel<<<dim3(42), dim3(256), 0, stream>>>(
        c1_w, c2_w, c3_w, wp1, wp2, wp3, zbuf, pooled, cntf);

    // All layers: wave tile 2x4x8 (ID=6, IH=10, PITCH=24, 6 DMA issues/cin).
    // L1: (2,1,64^3)->(2,32,32^3). r12 config (measured 33.6us): 4 spatial
    // waves (2x2x1), grid 2048.
    spline_block_kernel<256, 1, 1, 4, 2, 4, 8, 2, 2, 1, false>
        <<<dim3(2048), dim3(256), 0, stream>>>(
        x, (const float4*)wp1, c1_b, c1_kn, c1_sw, c1_w1, c1_w2, bn1_g, bn1_b,
        zbuf, h1, nullptr, nullptr, nullptr, nullptr, nullptr, nullptr,
        2, 32, 64, 64, 64, 128, 16, 4);
    // L2: (2,32,32^3)->(2,64,16^3). L3-shaped: CSPLIT=4 x NSW=1, G=8, CPG=8.
    // ntiles = 8x4x2 = 64, groups = 8 -> grid = 2*8*64 = 1024. Reduction runs
    // in 2 passes (scratch capacity).
    spline_block_kernel<256, 32, 4, 8, 2, 4, 8, 1, 1, 1, false>
        <<<dim3(1024), dim3(256), 0, stream>>>(
        h1, (const float4*)wp2, c2_b, c2_kn, c2_sw, c2_w1, c2_w2, bn2_g, bn2_b,
        zbuf, h2, nullptr, nullptr, nullptr, nullptr, nullptr, nullptr,
        2, 64, 32, 32, 32, 64, 8, 2);
    // L3: (2,64,16^3)->pooled[2,128] (FMEAN) + last-block fused fc -> d_out.
    // CSPLIT=4, grid 512. (r20 verbatim; PASSES=1 here)
    spline_block_kernel<256, 64, 4, 4, 2, 4, 8, 1, 1, 1, true>
        <<<dim3(512), dim3(256), 0, stream>>>(
        h2, (const float4*)wp3, c3_b, c3_kn, c3_sw, c3_w1, c3_w2, bn3_g, bn3_b,
        zbuf, pooled, fc1_w, fc1_b, fc2_w, fc2_b, (float*)d_out, (int*)cntf,
        2, 128, 16, 16, 16, 8, 2, 1);
}